// Round 16
// baseline (344.990 us; speedup 1.0000x reference)
//
#include <hip/hip_runtime.h>

typedef __bf16 bf16_t;
typedef __bf16 bf16x8 __attribute__((ext_vector_type(8)));
typedef float f32x4 __attribute__((ext_vector_type(4)));

#define MFMA(a, b, c) __builtin_amdgcn_mfma_f32_16x16x32_bf16((a), (b), (c), 0, 0, 0)

#define E_ROWS 640000
#define BM 256     // rows per tile: 8 waves x 32
#define NTILE 2500
#define GRID 250   // 10 tiles per block

static __device__ __forceinline__ bf16x8 cvt8(float4 a, float4 b) {
  bf16x8 r;
  r[0] = (bf16_t)a.x; r[1] = (bf16_t)a.y; r[2] = (bf16_t)a.z; r[3] = (bf16_t)a.w;
  r[4] = (bf16_t)b.x; r[5] = (bf16_t)b.y; r[6] = (bf16_t)b.z; r[7] = (bf16_t)b.w;
  return r;
}

static __device__ __forceinline__ unsigned int pk2(float a, float b) {
  unsigned short ua = __builtin_bit_cast(unsigned short, (bf16_t)a);
  unsigned short ub = __builtin_bit_cast(unsigned short, (bf16_t)b);
  return ((unsigned int)ub << 16) | ua;
}

static __device__ __forceinline__ void gload_lds16(const void* g, void* l) {
  __builtin_amdgcn_global_load_lds(
      (const __attribute__((address_space(1))) unsigned int*)g,
      (__attribute__((address_space(3))) unsigned int*)l, 16, 0, 0);
}

// Fragment-ordered weights in ws (table chunk = frag*64 + lane, 16B each):
//   Wm1: frags 0..63   Wm2: 64..95   Wu1: 96..159   Wu2: 160..191
// chunk holds 8 bf16: W[k][n], k = 32*ks + 8*(lane>>4) + j, n = 16*nb + (lane&15).
__global__ __launch_bounds__(256) void prep_weights(
    const float* __restrict__ Wm1, const float* __restrict__ Wm2,
    const float* __restrict__ Wu1, const float* __restrict__ Wu2,
    bf16_t* __restrict__ wt) {
  int c = blockIdx.x * 256 + threadIdx.x;
  if (c >= 12288) return;
  int lane = c & 63, f = c >> 6;
  const float* W; int base;
  if (f < 64)       { W = Wm1; base = 0;   }
  else if (f < 96)  { W = Wm2; base = 64;  }
  else if (f < 160) { W = Wu1; base = 96;  }
  else              { W = Wu2; base = 160; }
  int fl = f - base;
  int ks = fl >> 3, nb = fl & 7;
  int k0 = 32 * ks + 8 * (lane >> 4);
  int n  = 16 * nb + (lane & 15);
  bf16x8 v;
  #pragma unroll
  for (int j = 0; j < 8; ++j) v[j] = (bf16_t)W[(size_t)(k0 + j) * 128 + n];
  ((bf16x8*)wt)[c] = v;
}

#define STAGE96(tc0) { \
  _Pragma("unroll") \
  for (int i_ = 0; i_ < 12; ++i_) \
    gload_lds16((const char*)wt + ((size_t)((tc0) + i_ * 512 + tid)) * 16, \
                smem + (i_ * 512 + tid) * 16); }

#define LDW8(s, base, fl0) \
  s##0 = *(const bf16x8*)((base) + ((fl0) + 0) * 1024 + lane * 16); \
  s##1 = *(const bf16x8*)((base) + ((fl0) + 1) * 1024 + lane * 16); \
  s##2 = *(const bf16x8*)((base) + ((fl0) + 2) * 1024 + lane * 16); \
  s##3 = *(const bf16x8*)((base) + ((fl0) + 3) * 1024 + lane * 16); \
  s##4 = *(const bf16x8*)((base) + ((fl0) + 4) * 1024 + lane * 16); \
  s##5 = *(const bf16x8*)((base) + ((fl0) + 5) * 1024 + lane * 16); \
  s##6 = *(const bf16x8*)((base) + ((fl0) + 6) * 1024 + lane * 16); \
  s##7 = *(const bf16x8*)((base) + ((fl0) + 7) * 1024 + lane * 16);

#define ROUND(s, x0, x1) \
  acc00 = MFMA(s##0, x0, acc00); acc10 = MFMA(s##0, x1, acc10); \
  acc01 = MFMA(s##1, x0, acc01); acc11 = MFMA(s##1, x1, acc11); \
  acc02 = MFMA(s##2, x0, acc02); acc12 = MFMA(s##2, x1, acc12); \
  acc03 = MFMA(s##3, x0, acc03); acc13 = MFMA(s##3, x1, acc13); \
  acc04 = MFMA(s##4, x0, acc04); acc14 = MFMA(s##4, x1, acc14); \
  acc05 = MFMA(s##5, x0, acc05); acc15 = MFMA(s##5, x1, acc15); \
  acc06 = MFMA(s##6, x0, acc06); acc16 = MFMA(s##6, x1, acc16); \
  acc07 = MFMA(s##7, x0, acc07); acc17 = MFMA(s##7, x1, acc17);

#define ACCINIT(bp) { const float* bp_ = (bp) + g * 4; float4 q; \
  q = *(const float4*)(bp_ +   0); acc00 = (f32x4){q.x,q.y,q.z,q.w}; acc10 = acc00; \
  q = *(const float4*)(bp_ +  16); acc01 = (f32x4){q.x,q.y,q.z,q.w}; acc11 = acc01; \
  q = *(const float4*)(bp_ +  32); acc02 = (f32x4){q.x,q.y,q.z,q.w}; acc12 = acc02; \
  q = *(const float4*)(bp_ +  48); acc03 = (f32x4){q.x,q.y,q.z,q.w}; acc13 = acc03; \
  q = *(const float4*)(bp_ +  64); acc04 = (f32x4){q.x,q.y,q.z,q.w}; acc14 = acc04; \
  q = *(const float4*)(bp_ +  80); acc05 = (f32x4){q.x,q.y,q.z,q.w}; acc15 = acc05; \
  q = *(const float4*)(bp_ +  96); acc06 = (f32x4){q.x,q.y,q.z,q.w}; acc16 = acc06; \
  q = *(const float4*)(bp_ + 112); acc07 = (f32x4){q.x,q.y,q.z,q.w}; acc17 = acc07; }

#define RPK_H(av, nb, R) { \
  f32x4 v = av; \
  float e0 = v[0], e1 = v[1], e2 = v[2], e3 = v[3]; \
  if (R) { e0 = fmaxf(e0, 0.f); e1 = fmaxf(e1, 0.f); \
           e2 = fmaxf(e2, 0.f); e3 = fmaxf(e3, 0.f); } \
  uint2 w; w.x = pk2(e0, e1); w.y = pk2(e2, e3); \
  int dl = c + 16 * (2 * ((nb) & 1) + (g >> 1)); \
  *(uint2*)(myrep + (((nb) >> 1) * 64 + dl) * 16 + (g & 1) * 8) = w; }

#define WAITLDS asm volatile("s_waitcnt lgkmcnt(0)" ::: "memory");
#define VMCNT0  asm volatile("s_waitcnt vmcnt(0)" ::: "memory");
#define VMCNT16 asm volatile("s_waitcnt vmcnt(16)" ::: "memory");

#define REPACK(R, x) \
  RPK_H(acc00, 0, R) RPK_H(acc01, 1, R) RPK_H(acc02, 2, R) RPK_H(acc03, 3, R) \
  RPK_H(acc04, 4, R) RPK_H(acc05, 5, R) RPK_H(acc06, 6, R) RPK_H(acc07, 7, R) \
  WAITLDS \
  x##00 = *(const bf16x8*)(myrep + (0 * 64 + lane) * 16); \
  x##01 = *(const bf16x8*)(myrep + (1 * 64 + lane) * 16); \
  x##02 = *(const bf16x8*)(myrep + (2 * 64 + lane) * 16); \
  x##03 = *(const bf16x8*)(myrep + (3 * 64 + lane) * 16); \
  WAITLDS \
  RPK_H(acc10, 0, R) RPK_H(acc11, 1, R) RPK_H(acc12, 2, R) RPK_H(acc13, 3, R) \
  RPK_H(acc14, 4, R) RPK_H(acc15, 5, R) RPK_H(acc16, 6, R) RPK_H(acc17, 7, R) \
  WAITLDS \
  x##10 = *(const bf16x8*)(myrep + (0 * 64 + lane) * 16); \
  x##11 = *(const bf16x8*)(myrep + (1 * 64 + lane) * 16); \
  x##12 = *(const bf16x8*)(myrep + (2 * 64 + lane) * 16); \
  x##13 = *(const bf16x8*)(myrep + (3 * 64 + lane) * 16); \
  WAITLDS

#define LOADX(d0, d1, basep, kk, rr0, rr1) { \
  float4 a0 = *(const float4*)((basep) + (rr0) + (kk) * 32); \
  float4 a1 = *(const float4*)((basep) + (rr0) + (kk) * 32 + 4); \
  float4 b0 = *(const float4*)((basep) + (rr1) + (kk) * 32); \
  float4 b1 = *(const float4*)((basep) + (rr1) + (kk) * 32 + 4); \
  d0 = cvt8(a0, a1); d1 = cvt8(b0, b1); }

#define LOADX4(pfx, basep, rr0, rr1) \
  LOADX(pfx##00, pfx##10, basep, 0, rr0, rr1) \
  LOADX(pfx##01, pfx##11, basep, 1, rr0, rr1) \
  LOADX(pfx##02, pfx##12, basep, 2, rr0, rr1) \
  LOADX(pfx##03, pfx##13, basep, 3, rr0, rr1)

#define ST(av, mt, nb, rb) { f32x4 v = av; \
  *(float4*)(out + ((rb) + (mt) * 16 + c) * 128 + (nb) * 16 + g * 4) = \
      (float4){v[0], v[1], v[2], v[3]}; }

// first half of the chain: GEMM1 (Wm1) + GEMM2 (Wm2); x becomes msg B-frags
#define FIRST_HALF(hs, x) \
  ACCINIT(bm1) \
  LDW8(wa, W1, 0)   ROUND(wa, hs##00, hs##10) \
  LDW8(wa, W1, 8)   ROUND(wa, hs##01, hs##11) \
  LDW8(wa, W1, 16)  ROUND(wa, hs##02, hs##12) \
  LDW8(wa, W1, 24)  ROUND(wa, hs##03, hs##13) \
  LDW8(wa, W1, 32)  ROUND(wa, x##00, x##10) \
  LDW8(wa, W1, 40)  ROUND(wa, x##01, x##11) \
  LDW8(wa, W1, 48)  ROUND(wa, x##02, x##12) \
  LDW8(wa, W1, 56)  ROUND(wa, x##03, x##13) \
  REPACK(true, x) \
  ACCINIT(bm2) \
  LDW8(wa, W2, 0)   ROUND(wa, x##00, x##10) \
  LDW8(wa, W2, 8)   ROUND(wa, x##01, x##11) \
  LDW8(wa, W2, 16)  ROUND(wa, x##02, x##12) \
  LDW8(wa, W2, 24)  ROUND(wa, x##03, x##13) \
  REPACK(false, x)

// second half: GEMM3 (Wu1) + GEMM4 (Wu2) + store
#define SECOND_HALF(hs, x, rb) \
  ACCINIT(bu1) \
  LDW8(wa, W1, 0)   ROUND(wa, hs##00, hs##10) \
  LDW8(wa, W1, 8)   ROUND(wa, hs##01, hs##11) \
  LDW8(wa, W1, 16)  ROUND(wa, hs##02, hs##12) \
  LDW8(wa, W1, 24)  ROUND(wa, hs##03, hs##13) \
  LDW8(wa, W1, 32)  ROUND(wa, x##00, x##10) \
  LDW8(wa, W1, 40)  ROUND(wa, x##01, x##11) \
  LDW8(wa, W1, 48)  ROUND(wa, x##02, x##12) \
  LDW8(wa, W1, 56)  ROUND(wa, x##03, x##13) \
  REPACK(true, x) \
  ACCINIT(bu2) \
  LDW8(wa, W2, 0)   ROUND(wa, x##00, x##10) \
  LDW8(wa, W2, 8)   ROUND(wa, x##01, x##11) \
  LDW8(wa, W2, 16)  ROUND(wa, x##02, x##12) \
  LDW8(wa, W2, 24)  ROUND(wa, x##03, x##13) \
  ST(acc00, 0, 0, rb) ST(acc01, 0, 1, rb) ST(acc02, 0, 2, rb) ST(acc03, 0, 3, rb) \
  ST(acc04, 0, 4, rb) ST(acc05, 0, 5, rb) ST(acc06, 0, 6, rb) ST(acc07, 0, 7, rb) \
  ST(acc10, 1, 0, rb) ST(acc11, 1, 1, rb) ST(acc12, 1, 2, rb) ST(acc13, 1, 3, rb) \
  ST(acc14, 1, 4, rb) ST(acc15, 1, 5, rb) ST(acc16, 1, 6, rb) ST(acc17, 1, 7, rb)

// Persistent blocks: grid 250 x 10 tiles. Per tile: 4 barriers, 2 restages.
// Next-tile x loads fly under current compute (counted vmcnt(16) after Wu DMA,
// sched_barrier pins DMA-before-loads); stores drain under the Wm restage.
__global__ __launch_bounds__(512) void fused_mp(
    const float* __restrict__ hself, const float* __restrict__ hother,
    const bf16_t* __restrict__ wt,
    const float* __restrict__ bm1, const float* __restrict__ bm2,
    const float* __restrict__ bu1, const float* __restrict__ bu2,
    float* __restrict__ out) {
  __shared__ char smem[131072];

  const int tid = threadIdx.x;
  const int lane = tid & 63;
  const int wave = tid >> 6;
  const int c = lane & 15;
  const int g = lane >> 4;

  char* W1 = smem;            // frags 0..63  (Wm1 / Wu1)
  char* W2 = smem + 65536;    // frags 64..95 (Wm2 / Wu2)
  char* myrep = smem + 98304 + wave * 4096;

  bf16x8 hsA00, hsA01, hsA02, hsA03, hsA10, hsA11, hsA12, hsA13;
  bf16x8 xA00, xA01, xA02, xA03, xA10, xA11, xA12, xA13;
  bf16x8 hsB00, hsB01, hsB02, hsB03, hsB10, hsB11, hsB12, hsB13;
  bf16x8 xB00, xB01, xB02, xB03, xB10, xB11, xB12, xB13;
  f32x4 acc00, acc01, acc02, acc03, acc04, acc05, acc06, acc07;
  f32x4 acc10, acc11, acc12, acc13, acc14, acc15, acc16, acc17;
  bf16x8 wa0, wa1, wa2, wa3, wa4, wa5, wa6, wa7;

  // ---- prologue: stage Wm, load tile-0 x ----
  {
    STAGE96(0)
    __builtin_amdgcn_sched_barrier(0);
    size_t rb = (size_t)blockIdx.x * BM + wave * 32;
    size_t rr0 = (rb + c) * 128 + g * 8, rr1 = rr0 + 2048;
    LOADX4(hsA, hself, rr0, rr1)
    LOADX4(xA, hother, rr0, rr1)
    VMCNT0
    __syncthreads();  // Wm staged
  }

  #pragma unroll 1
  for (int it = 0; it < 5; ++it) {
    const int tA = blockIdx.x + it * 500;
    const int tB = tA + 250;
    int tN = tA + 500; if (tN >= NTILE) tN = 0;  // clamped dummy prefetch

    const size_t rbA = (size_t)tA * BM + wave * 32;
    const size_t rbB = (size_t)tB * BM + wave * 32;
    const size_t rbN = (size_t)tN * BM + wave * 32;
    const size_t r0B = (rbB + c) * 128 + g * 8, r1B = r0B + 2048;
    const size_t r0N = (rbN + c) * 128 + g * 8, r1N = r0N + 2048;

    // ================= body A (tile tA; prefetch x for tB) =================
    FIRST_HALF(hsA, xA)
    __syncthreads();                 // Wm reads done
    STAGE96(6144)                    // Wu -> LDS (async)
    __builtin_amdgcn_sched_barrier(0);
    LOADX4(xB, hother, r0B, r1B)     // 16 loads, younger than the 12 DMA
    VMCNT16                          // Wu DMA landed; xB still flying
    __syncthreads();
    SECOND_HALF(hsA, xA, rbA)
    __syncthreads();                 // Wu reads done
    LOADX4(hsB, hself, r0B, r1B)
    STAGE96(0)                       // Wm -> LDS
    VMCNT0                           // drain stores + hsB + DMA
    __syncthreads();

    // ================= body B (tile tB; prefetch x for tN) =================
    FIRST_HALF(hsB, xB)
    __syncthreads();
    STAGE96(6144)
    __builtin_amdgcn_sched_barrier(0);
    LOADX4(xA, hother, r0N, r1N)
    VMCNT16
    __syncthreads();
    SECOND_HALF(hsB, xB, rbB)
    __syncthreads();
    LOADX4(hsA, hself, r0N, r1N)
    STAGE96(0)
    VMCNT0
    __syncthreads();
  }
}

extern "C" void kernel_launch(void* const* d_in, const int* in_sizes, int n_in,
                              void* d_out, int out_size, void* d_ws, size_t ws_size,
                              hipStream_t stream) {
  const float* hself  = (const float*)d_in[0];
  const float* hother = (const float*)d_in[1];
  const float* Wm1 = (const float*)d_in[2];
  const float* bm1 = (const float*)d_in[3];
  const float* Wm2 = (const float*)d_in[4];
  const float* bm2 = (const float*)d_in[5];
  const float* Wu1 = (const float*)d_in[6];
  const float* bu1 = (const float*)d_in[7];
  const float* Wu2 = (const float*)d_in[8];
  const float* bu2 = (const float*)d_in[9];
  float* out = (float*)d_out;
  bf16_t* wt = (bf16_t*)d_ws;  // 196608 B of fragment-ordered bf16 weights

  prep_weights<<<48, 256, 0, stream>>>(Wm1, Wm2, Wu1, Wu2, wt);
  fused_mp<<<GRID, 512, 0, stream>>>(hself, hother, wt,
                                     bm1, bm2, bu1, bu2, out);
}

// Round 17
// 340.935 us; speedup vs baseline: 1.0119x; 1.0119x over previous
//
#include <hip/hip_runtime.h>

typedef __bf16 bf16_t;
typedef __bf16 bf16x8 __attribute__((ext_vector_type(8)));
typedef float f32x4 __attribute__((ext_vector_type(4)));

#define MFMA(a, b, c) __builtin_amdgcn_mfma_f32_16x16x32_bf16((a), (b), (c), 0, 0, 0)

#define E_ROWS 640000
#define BM 256     // rows per tile: 8 waves x 32
#define NTILE 2500
#define GRID 250   // 10 tiles per block (A/B alternation x 5)

static __device__ __forceinline__ bf16x8 cvt8(float4 a, float4 b) {
  bf16x8 r;
  r[0] = (bf16_t)a.x; r[1] = (bf16_t)a.y; r[2] = (bf16_t)a.z; r[3] = (bf16_t)a.w;
  r[4] = (bf16_t)b.x; r[5] = (bf16_t)b.y; r[6] = (bf16_t)b.z; r[7] = (bf16_t)b.w;
  return r;
}

static __device__ __forceinline__ unsigned int pk2(float a, float b) {
  unsigned short ua = __builtin_bit_cast(unsigned short, (bf16_t)a);
  unsigned short ub = __builtin_bit_cast(unsigned short, (bf16_t)b);
  return ((unsigned int)ub << 16) | ua;
}

static __device__ __forceinline__ void gload_lds16(const void* g, void* l) {
  __builtin_amdgcn_global_load_lds(
      (const __attribute__((address_space(1))) unsigned int*)g,
      (__attribute__((address_space(3))) unsigned int*)l, 16, 0, 0);
}

// Fragment-ordered weights in ws (table chunk = frag*64 + lane, 16B each):
//   Wm1: frags 0..63   Wm2: 64..95   Wu1: 96..159   Wu2: 160..191
// chunk holds 8 bf16: W[k][n], k = 32*ks + 8*(lane>>4) + j, n = 16*nb + (lane&15).
__global__ __launch_bounds__(256) void prep_weights(
    const float* __restrict__ Wm1, const float* __restrict__ Wm2,
    const float* __restrict__ Wu1, const float* __restrict__ Wu2,
    bf16_t* __restrict__ wt) {
  int c = blockIdx.x * 256 + threadIdx.x;
  if (c >= 12288) return;
  int lane = c & 63, f = c >> 6;
  const float* W; int base;
  if (f < 64)       { W = Wm1; base = 0;   }
  else if (f < 96)  { W = Wm2; base = 64;  }
  else if (f < 160) { W = Wu1; base = 96;  }
  else              { W = Wu2; base = 160; }
  int fl = f - base;
  int ks = fl >> 3, nb = fl & 7;
  int k0 = 32 * ks + 8 * (lane >> 4);
  int n  = 16 * nb + (lane & 15);
  bf16x8 v;
  #pragma unroll
  for (int j = 0; j < 8; ++j) v[j] = (bf16_t)W[(size_t)(k0 + j) * 128 + n];
  ((bf16x8*)wt)[c] = v;
}

#define STAGE96(tc0) { \
  _Pragma("unroll") \
  for (int i_ = 0; i_ < 12; ++i_) \
    gload_lds16((const char*)wt + ((size_t)((tc0) + i_ * 512 + tid)) * 16, \
                smem + (i_ * 512 + tid) * 16); }

#define LDW8(s, base, fl0) \
  s##0 = *(const bf16x8*)((base) + ((fl0) + 0) * 1024 + lane * 16); \
  s##1 = *(const bf16x8*)((base) + ((fl0) + 1) * 1024 + lane * 16); \
  s##2 = *(const bf16x8*)((base) + ((fl0) + 2) * 1024 + lane * 16); \
  s##3 = *(const bf16x8*)((base) + ((fl0) + 3) * 1024 + lane * 16); \
  s##4 = *(const bf16x8*)((base) + ((fl0) + 4) * 1024 + lane * 16); \
  s##5 = *(const bf16x8*)((base) + ((fl0) + 5) * 1024 + lane * 16); \
  s##6 = *(const bf16x8*)((base) + ((fl0) + 6) * 1024 + lane * 16); \
  s##7 = *(const bf16x8*)((base) + ((fl0) + 7) * 1024 + lane * 16);

#define ROUND(s, x0, x1) \
  acc00 = MFMA(s##0, x0, acc00); acc10 = MFMA(s##0, x1, acc10); \
  acc01 = MFMA(s##1, x0, acc01); acc11 = MFMA(s##1, x1, acc11); \
  acc02 = MFMA(s##2, x0, acc02); acc12 = MFMA(s##2, x1, acc12); \
  acc03 = MFMA(s##3, x0, acc03); acc13 = MFMA(s##3, x1, acc13); \
  acc04 = MFMA(s##4, x0, acc04); acc14 = MFMA(s##4, x1, acc14); \
  acc05 = MFMA(s##5, x0, acc05); acc15 = MFMA(s##5, x1, acc15); \
  acc06 = MFMA(s##6, x0, acc06); acc16 = MFMA(s##6, x1, acc16); \
  acc07 = MFMA(s##7, x0, acc07); acc17 = MFMA(s##7, x1, acc17);

#define ACCINIT(bp) { const float* bp_ = (bp) + g * 4; float4 q; \
  q = *(const float4*)(bp_ +   0); acc00 = (f32x4){q.x,q.y,q.z,q.w}; acc10 = acc00; \
  q = *(const float4*)(bp_ +  16); acc01 = (f32x4){q.x,q.y,q.z,q.w}; acc11 = acc01; \
  q = *(const float4*)(bp_ +  32); acc02 = (f32x4){q.x,q.y,q.z,q.w}; acc12 = acc02; \
  q = *(const float4*)(bp_ +  48); acc03 = (f32x4){q.x,q.y,q.z,q.w}; acc13 = acc03; \
  q = *(const float4*)(bp_ +  64); acc04 = (f32x4){q.x,q.y,q.z,q.w}; acc14 = acc04; \
  q = *(const float4*)(bp_ +  80); acc05 = (f32x4){q.x,q.y,q.z,q.w}; acc15 = acc05; \
  q = *(const float4*)(bp_ +  96); acc06 = (f32x4){q.x,q.y,q.z,q.w}; acc16 = acc06; \
  q = *(const float4*)(bp_ + 112); acc07 = (f32x4){q.x,q.y,q.z,q.w}; acc17 = acc07; }

#define RPK_H(av, nb, R) { \
  f32x4 v = av; \
  float e0 = v[0], e1 = v[1], e2 = v[2], e3 = v[3]; \
  if (R) { e0 = fmaxf(e0, 0.f); e1 = fmaxf(e1, 0.f); \
           e2 = fmaxf(e2, 0.f); e3 = fmaxf(e3, 0.f); } \
  uint2 w; w.x = pk2(e0, e1); w.y = pk2(e2, e3); \
  int dl = c + 16 * (2 * ((nb) & 1) + (g >> 1)); \
  *(uint2*)(myrep + (((nb) >> 1) * 64 + dl) * 16 + (g & 1) * 8) = w; }

#define WAITLDS asm volatile("s_waitcnt lgkmcnt(0)" ::: "memory");
#define VMCNT0  asm volatile("s_waitcnt vmcnt(0)" ::: "memory");
#define VMCNT16 asm volatile("s_waitcnt vmcnt(16)" ::: "memory");
#define SBAR    __builtin_amdgcn_sched_barrier(0);

#define REPACK(R, x) \
  RPK_H(acc00, 0, R) RPK_H(acc01, 1, R) RPK_H(acc02, 2, R) RPK_H(acc03, 3, R) \
  RPK_H(acc04, 4, R) RPK_H(acc05, 5, R) RPK_H(acc06, 6, R) RPK_H(acc07, 7, R) \
  WAITLDS \
  x##00 = *(const bf16x8*)(myrep + (0 * 64 + lane) * 16); \
  x##01 = *(const bf16x8*)(myrep + (1 * 64 + lane) * 16); \
  x##02 = *(const bf16x8*)(myrep + (2 * 64 + lane) * 16); \
  x##03 = *(const bf16x8*)(myrep + (3 * 64 + lane) * 16); \
  WAITLDS \
  RPK_H(acc10, 0, R) RPK_H(acc11, 1, R) RPK_H(acc12, 2, R) RPK_H(acc13, 3, R) \
  RPK_H(acc14, 4, R) RPK_H(acc15, 5, R) RPK_H(acc16, 6, R) RPK_H(acc17, 7, R) \
  WAITLDS \
  x##10 = *(const bf16x8*)(myrep + (0 * 64 + lane) * 16); \
  x##11 = *(const bf16x8*)(myrep + (1 * 64 + lane) * 16); \
  x##12 = *(const bf16x8*)(myrep + (2 * 64 + lane) * 16); \
  x##13 = *(const bf16x8*)(myrep + (3 * 64 + lane) * 16); \
  WAITLDS

#define LOADX(d0, d1, basep, kk, rr0, rr1) { \
  float4 a0 = *(const float4*)((basep) + (rr0) + (kk) * 32); \
  float4 a1 = *(const float4*)((basep) + (rr0) + (kk) * 32 + 4); \
  float4 b0 = *(const float4*)((basep) + (rr1) + (kk) * 32); \
  float4 b1 = *(const float4*)((basep) + (rr1) + (kk) * 32 + 4); \
  d0 = cvt8(a0, a1); d1 = cvt8(b0, b1); }

#define LOADX4(pfx, basep, rr0, rr1) \
  LOADX(pfx##00, pfx##10, basep, 0, rr0, rr1) \
  LOADX(pfx##01, pfx##11, basep, 1, rr0, rr1) \
  LOADX(pfx##02, pfx##12, basep, 2, rr0, rr1) \
  LOADX(pfx##03, pfx##13, basep, 3, rr0, rr1)

#define ST(av, mt, nb, rb) { f32x4 v = av; \
  *(float4*)(out + ((rb) + (mt) * 16 + c) * 128 + (nb) * 16 + g * 4) = \
      (float4){v[0], v[1], v[2], v[3]}; }

#define STORE16(rb) \
  ST(acc00, 0, 0, rb) ST(acc01, 0, 1, rb) ST(acc02, 0, 2, rb) ST(acc03, 0, 3, rb) \
  ST(acc04, 0, 4, rb) ST(acc05, 0, 5, rb) ST(acc06, 0, 6, rb) ST(acc07, 0, 7, rb) \
  ST(acc10, 1, 0, rb) ST(acc11, 1, 1, rb) ST(acc12, 1, 2, rb) ST(acc13, 1, 3, rb) \
  ST(acc14, 1, 4, rb) ST(acc15, 1, 5, rb) ST(acc16, 1, 6, rb) ST(acc17, 1, 7, rb)

// GEMM1+GEMM2 (Wm1, Wm2); x in = [ho|h1|msg] staging, x out = msg B-frags
#define FIRST_HALF(x) \
  ACCINIT(bm1) \
  LDW8(wa, W1, 0)   ROUND(wa, hs00, hs10) \
  LDW8(wa, W1, 8)   ROUND(wa, hs01, hs11) \
  LDW8(wa, W1, 16)  ROUND(wa, hs02, hs12) \
  LDW8(wa, W1, 24)  ROUND(wa, hs03, hs13) \
  LDW8(wa, W1, 32)  ROUND(wa, x##00, x##10) \
  LDW8(wa, W1, 40)  ROUND(wa, x##01, x##11) \
  LDW8(wa, W1, 48)  ROUND(wa, x##02, x##12) \
  LDW8(wa, W1, 56)  ROUND(wa, x##03, x##13) \
  REPACK(true, x) \
  ACCINIT(bm2) \
  LDW8(wa, W2, 0)   ROUND(wa, x##00, x##10) \
  LDW8(wa, W2, 8)   ROUND(wa, x##01, x##11) \
  LDW8(wa, W2, 16)  ROUND(wa, x##02, x##12) \
  LDW8(wa, W2, 24)  ROUND(wa, x##03, x##13) \
  REPACK(false, x)

// GEMM3+GEMM4 (Wu1, Wu2); NO stores (they issue after the next restage DMA)
#define SECOND_HALF_NOST(x) \
  ACCINIT(bu1) \
  LDW8(wa, W1, 0)   ROUND(wa, hs00, hs10) \
  LDW8(wa, W1, 8)   ROUND(wa, hs01, hs11) \
  LDW8(wa, W1, 16)  ROUND(wa, hs02, hs12) \
  LDW8(wa, W1, 24)  ROUND(wa, hs03, hs13) \
  LDW8(wa, W1, 32)  ROUND(wa, x##00, x##10) \
  LDW8(wa, W1, 40)  ROUND(wa, x##01, x##11) \
  LDW8(wa, W1, 48)  ROUND(wa, x##02, x##12) \
  LDW8(wa, W1, 56)  ROUND(wa, x##03, x##13) \
  REPACK(true, x) \
  ACCINIT(bu2) \
  LDW8(wa, W2, 0)   ROUND(wa, x##00, x##10) \
  LDW8(wa, W2, 8)   ROUND(wa, x##01, x##11) \
  LDW8(wa, W2, 16)  ROUND(wa, x##02, x##12) \
  LDW8(wa, W2, 24)  ROUND(wa, x##03, x##13)

// Persistent blocks (grid 250, 10 tiles each as 5x{A,B}).
// Overlap scheme per tile:
//  - next tile's ho prefetch (xNEXT regs) flies under GEMM3/4 [vmcnt(16)]
//  - out stores issue AFTER the Wm restage DMA and drain under the next
//    tile's GEMM1 [vmcnt(16): 12 older DMA drained, 16 stores left flying]
//  - hs reloaded serially per tile (single buffer; prefetching it spilled in
//    R16: 512-thr blocks force <=256 unified regs/wave, xB-only fits ~222)
__global__ __launch_bounds__(512) void fused_mp(
    const float* __restrict__ hself, const float* __restrict__ hother,
    const bf16_t* __restrict__ wt,
    const float* __restrict__ bm1, const float* __restrict__ bm2,
    const float* __restrict__ bu1, const float* __restrict__ bu2,
    float* __restrict__ out) {
  __shared__ char smem[131072];

  const int tid = threadIdx.x;
  const int lane = tid & 63;
  const int wave = tid >> 6;
  const int c = lane & 15;
  const int g = lane >> 4;

  char* W1 = smem;            // frags 0..63  (Wm1 / Wu1)
  char* W2 = smem + 65536;    // frags 64..95 (Wm2 / Wu2)
  char* myrep = smem + 98304 + wave * 4096;

  bf16x8 hs00, hs01, hs02, hs03, hs10, hs11, hs12, hs13;
  bf16x8 xA00, xA01, xA02, xA03, xA10, xA11, xA12, xA13;
  bf16x8 xB00, xB01, xB02, xB03, xB10, xB11, xB12, xB13;
  f32x4 acc00, acc01, acc02, acc03, acc04, acc05, acc06, acc07;
  f32x4 acc10, acc11, acc12, acc13, acc14, acc15, acc16, acc17;
  bf16x8 wa0, wa1, wa2, wa3, wa4, wa5, wa6, wa7;

  // ---- prologue: stage Wm, prefetch tile-0 ho ----
  {
    STAGE96(0)
    SBAR
    size_t rb = (size_t)blockIdx.x * BM + wave * 32;
    size_t rr0 = (rb + c) * 128 + g * 8, rr1 = rr0 + 2048;
    LOADX4(xA, hother, rr0, rr1)
    VMCNT0
    __syncthreads();  // Wm staged
  }

  #pragma unroll 1
  for (int it = 0; it < 5; ++it) {
    const int tA = blockIdx.x + it * 500;
    const int tB = tA + 250;

    const size_t rbA = (size_t)tA * BM + wave * 32;
    const size_t rbB = (size_t)tB * BM + wave * 32;
    const size_t r0A = (rbA + c) * 128 + g * 8, r1A = r0A + 2048;
    const size_t r0B = (rbB + c) * 128 + g * 8, r1B = r0B + 2048;

    // ================= body A (tile tA; prefetch ho for tB) ================
    LOADX4(hs, hself, r0A, r1A)      // serial hs load for tA
    FIRST_HALF(xA)
    __syncthreads();                 // Wm reads done
    STAGE96(6144)                    // Wu -> LDS (async)
    SBAR
    LOADX4(xB, hother, r0B, r1B)     // prefetch: 16 loads younger than 12 DMA
    SBAR
    VMCNT16                          // Wu DMA landed; xB still flying
    __syncthreads();
    SECOND_HALF_NOST(xA)
    __syncthreads();                 // Wu reads done
    STAGE96(0)                       // Wm -> LDS (async)
    SBAR
    STORE16(rbA)                     // stores younger than the 12 DMA
    SBAR
    VMCNT16                          // Wm DMA landed; stores still flying
    __syncthreads();

    // ================= body B (tile tB; prefetch ho for next pair) =========
    LOADX4(hs, hself, r0B, r1B)      // serial hs load for tB
    FIRST_HALF(xB)
    __syncthreads();
    STAGE96(6144)
    SBAR
    if (it < 4) {
      const size_t rbN = (size_t)(tA + 500) * BM + wave * 32;
      const size_t r0N = (rbN + c) * 128 + g * 8, r1N = r0N + 2048;
      LOADX4(xA, hother, r0N, r1N)
      SBAR
      VMCNT16
    } else {
      VMCNT0                         // no prefetch on last pair
    }
    __syncthreads();
    SECOND_HALF_NOST(xB)
    __syncthreads();
    STAGE96(0)
    SBAR
    STORE16(rbB)
    SBAR
    VMCNT16
    __syncthreads();
  }
}

extern "C" void kernel_launch(void* const* d_in, const int* in_sizes, int n_in,
                              void* d_out, int out_size, void* d_ws, size_t ws_size,
                              hipStream_t stream) {
  const float* hself  = (const float*)d_in[0];
  const float* hother = (const float*)d_in[1];
  const float* Wm1 = (const float*)d_in[2];
  const float* bm1 = (const float*)d_in[3];
  const float* Wm2 = (const float*)d_in[4];
  const float* bm2 = (const float*)d_in[5];
  const float* Wu1 = (const float*)d_in[6];
  const float* bu1 = (const float*)d_in[7];
  const float* Wu2 = (const float*)d_in[8];
  const float* bu2 = (const float*)d_in[9];
  float* out = (float*)d_out;
  bf16_t* wt = (bf16_t*)d_ws;  // 196608 B of fragment-ordered bf16 weights

  prep_weights<<<48, 256, 0, stream>>>(Wm1, Wm2, Wu1, Wu2, wt);
  fused_mp<<<GRID, 512, 0, stream>>>(hself, hother, wt,
                                     bm1, bm2, bu1, bu2, out);
}